// Round 4
// baseline (453.968 us; speedup 1.0000x reference)
//
#include <hip/hip_runtime.h>
#include <hip/hip_bf16.h>
#include <cstdint>

// Problem constants (bsz=8, h=1024, seq=1024, K=2 taps)
#define HSZ   1024
#define SEQ   1024
#define NTOT  8192      // bsz*seq
#define K2    2048      // 2*h (i,tap interleaved)

typedef __attribute__((ext_vector_type(8))) short bf16x8;
typedef __attribute__((ext_vector_type(4))) float f32x4;

#define WAITVM(N) asm volatile("s_waitcnt vmcnt(" #N ")" ::: "memory")

__device__ __forceinline__ unsigned f2bf(float x) {
  unsigned u = __builtin_bit_cast(unsigned, x);
  return (u + 0x7fffu + ((u >> 16) & 1u)) >> 16;   // RNE, inputs are finite
}
__device__ __forceinline__ float fsig(float x)  { return 1.f / (1.f + __expf(-x)); }
__device__ __forceinline__ float ftanh(float x) { return 1.f - 2.f / (__expf(2.f * x) + 1.f); }

__device__ __forceinline__ void gload_lds16(const void* g, void* l) {
  __builtin_amdgcn_global_load_lds(
      (const __attribute__((address_space(1))) unsigned*)g,
      (__attribute__((address_space(3))) unsigned*)l, 16, 0, 0);
}

// ---- prep 1: weight fp32 -> bf16, layout unchanged (o, k=2i+tap contiguous) ----
__global__ void conv_weight_kernel(const float* __restrict__ w, unsigned* __restrict__ wb) {
  int idx = (blockIdx.x * 256 + threadIdx.x) * 4;    // 8192 blocks * 1024 floats = exact
  f32x4 v = *(const f32x4*)(w + idx);
  uint2 o;
  o.x = f2bf(v.x) | (f2bf(v.y) << 16);
  o.y = f2bf(v.z) | (f2bf(v.w) << 16);
  *(uint2*)(wb + (idx >> 1)) = o;
}

// ---- prep 2: Bd[n][k] bf16, k=2i+tap: tap0 = x[t-1] (z0h at t=0), tap1 = x[t] ----
__global__ void build_bdup_kernel(const float* __restrict__ z1ss, const float* __restrict__ z0,
                                  unsigned* __restrict__ bd) {
  __shared__ float tile[32 * 34];                    // [ii][j], j in [0,33) = t0-1..t0+31
  const int tid = threadIdx.x;
  const int n0 = blockIdx.x * 32;                    // 256 n-tiles (never cross batch)
  const int i0 = blockIdx.y * 32;                    // 32 i-tiles
  const int b  = n0 >> 10;
  const int t0 = n0 & 1023;
  const int ii = tid >> 3, js = tid & 7;
  const float* zrow = z1ss + (b * 2048 + i0 + ii) * 1024;
  const float z0v = z0[b * 2048 + i0 + ii];
#pragma unroll
  for (int p = 0; p < 5; ++p) {
    int j = js + p * 8;
    if (j < 33) {
      int gt = t0 - 1 + j;
      tile[ii * 34 + j] = (gt < 0) ? z0v : zrow[gt];
    }
  }
  __syncthreads();
  const int i2 = tid & 31, ts = tid >> 5;
#pragma unroll
  for (int p = 0; p < 4; ++p) {
    int tt = ts + p * 8;
    float prev = tile[i2 * 34 + tt];                 // x[t-1] (or z0h)
    float cur  = tile[i2 * 34 + tt + 1];             // x[t]
    bd[(n0 + tt) * 1024 + i0 + i2] = f2bf(prev) | (f2bf(cur) << 16);  // shorts 2i / 2i+1
  }
}

// ---- GEMM + fused LSTM epilogue ----
// 128x128 m97-family structure, BK=32, now with a depth-2 prefetch pipeline:
// 3 LDS tile-buffers (48 KB -> still 3 blocks/CU). Per K-step t:
//   stage(t+2) -> buf[(t+2)%3]; compute(t) from buf[t%3];
//   vmcnt(4) (tile t+1 landed; t+2 stays IN FLIGHT across the barrier); s_barrier.
// Counted vmcnt never drains to 0 in the main loop (T3+T4); barrier count
// unchanged (64/block) but each barrier's wait is pre-satisfied by ~2 steps
// of compute lookahead instead of exposing full load latency.
// Race-audit: stage buf (t+2)%3 != compute bufs t%3 / (t+1)%3; compute(t-1)
// is barrier-retired before step t (barrier sits AFTER compute in the body).
// LDS layout per tile (A and B): [128 rows][4 slots of 8 shorts],
//   stored chunk at slot = chunk ^ ((row>>1)&3)  -> DMA-linear dest with
//   pre-swizzled global source (rule 21), ds_read_b128 conflict-free
//   (8 lanes span all 32 banks, 2-way across halves = free, m136).
__launch_bounds__(256, 3)
__global__ void lstm_gemm_kernel(const unsigned short* __restrict__ Wb,
                                 const unsigned short* __restrict__ Bd,
                                 const float* __restrict__ uss,
                                 const float* __restrict__ z1ss,
                                 const float* __restrict__ z0,
                                 const float* __restrict__ bias,
                                 float* __restrict__ out);

template<int BUF, int SB, int VMN>
__device__ __forceinline__ void kstep(
    unsigned short* __restrict__ Asm_, unsigned short* __restrict__ Bsm_,
    const unsigned short* aG0, const unsigned short* aG1,
    const unsigned short* bG0, const unsigned short* bG1,
    int kofs, int wave, int l15, int slotOfs,
    f32x4 (&acc)[4][2][2])
{
  if constexpr (SB >= 0) {
    // stage tile (kofs/32) into buffer SB: 2 A + 2 B gloads per wave
    unsigned short* la0 = Asm_ + SB * 4096 + (wave * 2 + 0) * 512;
    unsigned short* la1 = Asm_ + SB * 4096 + (wave * 2 + 1) * 512;
    unsigned short* lb0 = Bsm_ + SB * 4096 + (wave * 2 + 0) * 512;
    unsigned short* lb1 = Bsm_ + SB * 4096 + (wave * 2 + 1) * 512;
    gload_lds16(aG0 + kofs, la0);
    gload_lds16(aG1 + kofs, la1);
    gload_lds16(bG0 + kofs, lb0);
    gload_lds16(bG1 + kofs, lb1);
  }
  const unsigned short* At = Asm_ + BUF * 4096;
  const unsigned short* Bt = Bsm_ + BUF * 4096;
  bf16x8 bf[2];
#pragma unroll
  for (int nt = 0; nt < 2; ++nt)
    bf[nt] = *(const bf16x8*)(Bt + (wave * 32 + nt * 16 + l15) * 32 + slotOfs);
#pragma unroll
  for (int g = 0; g < 4; ++g)
#pragma unroll
    for (int h = 0; h < 2; ++h) {
      bf16x8 af = *(const bf16x8*)(At + ((g * 2 + h) * 16 + l15) * 32 + slotOfs);
#pragma unroll
      for (int nt = 0; nt < 2; ++nt)
        acc[g][h][nt] = __builtin_amdgcn_mfma_f32_16x16x32_bf16(af, bf[nt], acc[g][h][nt], 0, 0, 0);
    }
  if constexpr (VMN == 4) WAITVM(4);
  else if constexpr (VMN == 0) WAITVM(0);
  if constexpr (VMN >= 0) {
    __builtin_amdgcn_s_barrier();
    __builtin_amdgcn_sched_barrier(0);
  }
}

__launch_bounds__(256, 3)
__global__ void lstm_gemm_kernel(const unsigned short* __restrict__ Wb,
                                 const unsigned short* __restrict__ Bd,
                                 const float* __restrict__ uss,
                                 const float* __restrict__ z1ss,
                                 const float* __restrict__ z0,
                                 const float* __restrict__ bias,
                                 float* __restrict__ out) {
  __shared__ unsigned short Asm_[3 * 4096];   // 3 bufs x 128 rows x 32 k = 24 KB
  __shared__ unsigned short Bsm_[3 * 4096];   // 24 KB
  const int tid  = threadIdx.x;
  const int wave = tid >> 6, lane = tid & 63;
  const int l15  = lane & 15, quad = lane >> 4;
  const int c0 = blockIdx.y * 32;
  const int n0 = blockIdx.x * 128;

  // staging descriptors: per wave 2 A + 2 B insts, each covers 16 rows x 32k
  // (1 KiB LDS). unit u = (wave*2+j)*64+lane; row=u>>2 in [0,128), slot=u&3;
  // global chunk = slot ^ ((row>>1)&3)  (pre-swizzled source).
  const unsigned short *aG0, *aG1, *bG0, *bG1;
  {
    const int u0 = (wave * 2 + 0) * 64 + lane;
    const int r0 = u0 >> 2;
    const int c0k = ((u0 & 3) ^ ((r0 >> 1) & 3)) * 8;
    const int wr0 = (r0 >> 5) * 1024 + c0 + (r0 & 31);
    aG0 = Wb + (size_t)wr0 * K2 + c0k;
    bG0 = Bd + (size_t)(n0 + r0) * K2 + c0k;
    const int u1 = (wave * 2 + 1) * 64 + lane;
    const int r1 = u1 >> 2;
    const int c1k = ((u1 & 3) ^ ((r1 >> 1) & 3)) * 8;
    const int wr1 = (r1 >> 5) * 1024 + c0 + (r1 & 31);
    aG1 = Wb + (size_t)wr1 * K2 + c1k;
    bG1 = Bd + (size_t)(n0 + r1) * K2 + c1k;
  }

  // fragment read slot: read rows have row&15 == l15 (bases mult of 16),
  // so s(row) = (row>>1)&3 = (l15>>1)&3 for every fragment.
  const int slotOfs = ((quad ^ ((l15 >> 1) & 3)) << 3);

  f32x4 acc[4][2][2];
#pragma unroll
  for (int g = 0; g < 4; ++g)
#pragma unroll
    for (int h = 0; h < 2; ++h)
#pragma unroll
      for (int nt = 0; nt < 2; ++nt)
        acc[g][h][nt] = (f32x4){0.f, 0.f, 0.f, 0.f};

  // ---- prologue: stage tiles 0 and 1 ----
  gload_lds16(aG0,      Asm_ + 0 * 4096 + (wave * 2 + 0) * 512);
  gload_lds16(aG1,      Asm_ + 0 * 4096 + (wave * 2 + 1) * 512);
  gload_lds16(bG0,      Bsm_ + 0 * 4096 + (wave * 2 + 0) * 512);
  gload_lds16(bG1,      Bsm_ + 0 * 4096 + (wave * 2 + 1) * 512);
  gload_lds16(aG0 + 32, Asm_ + 1 * 4096 + (wave * 2 + 0) * 512);
  gload_lds16(aG1 + 32, Asm_ + 1 * 4096 + (wave * 2 + 1) * 512);
  gload_lds16(bG0 + 32, Bsm_ + 1 * 4096 + (wave * 2 + 0) * 512);
  gload_lds16(bG1 + 32, Bsm_ + 1 * 4096 + (wave * 2 + 1) * 512);
  WAITVM(4);                                         // tile 0 resident (1 in flight)
  __builtin_amdgcn_s_barrier();
  __builtin_amdgcn_sched_barrier(0);

  // ---- main loop: 64 K-steps of 32; steps t=0..59 (x3 unroll), tail 60..63 ----
  int kofs = 2 * 32;                                 // stage target = tile t+2
  for (int it = 0; it < 20; ++it) {
    kstep<0, 2, 4>(Asm_, Bsm_, aG0, aG1, bG0, bG1, kofs,      wave, l15, slotOfs, acc);
    kstep<1, 0, 4>(Asm_, Bsm_, aG0, aG1, bG0, bG1, kofs + 32, wave, l15, slotOfs, acc);
    kstep<2, 1, 4>(Asm_, Bsm_, aG0, aG1, bG0, bG1, kofs + 64, wave, l15, slotOfs, acc);
    kofs += 96;
  }
  kstep<0, 2, 4>(Asm_, Bsm_, aG0, aG1, bG0, bG1, kofs,      wave, l15, slotOfs, acc); // t=60 stages 62
  kstep<1, 0, 4>(Asm_, Bsm_, aG0, aG1, bG0, bG1, kofs + 32, wave, l15, slotOfs, acc); // t=61 stages 63
  kstep<2, -1, 0>(Asm_, Bsm_, aG0, aG1, bG0, bG1, 0, wave, l15, slotOfs, acc);        // t=62
  kstep<0, -1, -1>(Asm_, Bsm_, aG0, aG1, bG0, bG1, 0, wave, l15, slotOfs, acc);       // t=63

  // epilogue: C/D layout col=lane&15 (n), row=quad*4+reg (m); all 4 gates register-local
#pragma unroll
  for (int h = 0; h < 2; ++h) {
#pragma unroll
    for (int r = 0; r < 4; ++r) {
      const int c = c0 + h * 16 + quad * 4 + r;
      const float bv0 = bias[c], bv1 = bias[1024 + c], bv2 = bias[2048 + c], bv3 = bias[3072 + c];
#pragma unroll
      for (int nt = 0; nt < 2; ++nt) {
        const int n = n0 + wave * 32 + nt * 16 + l15;
        const int b = n >> 10, t = n & 1023;
        const int ub = b * 4194304 + c * 1024 + t;   // uss[b][g*1024+c][t], gate stride 1048576
        float p0 = acc[0][h][nt][r] + uss[ub]           + bv0;
        float p1 = acc[1][h][nt][r] + uss[ub + 1048576] + bv1;
        float p2 = acc[2][h][nt][r] + uss[ub + 2097152] + bv2;
        float p3 = acc[3][h][nt][r] + uss[ub + 3145728] + bv3;
        float it = fsig(p0), ot = fsig(p1), g_ = ftanh(p2), ft = fsig(p3);
        float zc = t ? z1ss[(b * 2048 + 1024 + c) * 1024 + t - 1]
                     : z0[b * 2048 + 1024 + c];
        float ct = ft * zc + it * g_;
        float ht = ot * ftanh(ct);
        const int ob = (b * 2048 + c) * 1024 + t;
        out[ob] = ht;
        out[ob + 1048576] = ct;
      }
    }
  }
}

// ---- slow-but-correct fallback if ws too small ----
__global__ void naive_kernel(const float* __restrict__ z1ss, const float* __restrict__ uss,
                             const float* __restrict__ z0, const float* __restrict__ w,
                             const float* __restrict__ bias, float* __restrict__ out) {
  int idx = blockIdx.x * 256 + threadIdx.x;          // (b,c,t)
  int b = idx >> 20, c = (idx >> 10) & 1023, t = idx & 1023;
  float s0 = 0.f, s1 = 0.f, s2 = 0.f, s3 = 0.f;
  const float* xb = z1ss + b * 2097152;
  for (int i = 0; i < 1024; ++i) {
    float cur  = xb[i * 1024 + t];
    float prev = t ? xb[i * 1024 + t - 1] : z0[b * 2048 + i];
    const float* wr = w + c * 2048 + i * 2;
    s0 += wr[0]       * prev + wr[1]       * cur;
    s1 += wr[2097152] * prev + wr[2097153] * cur;
    s2 += wr[4194304] * prev + wr[4194305] * cur;
    s3 += wr[6291456] * prev + wr[6291457] * cur;
  }
  int ub = b * 4194304 + c * 1024 + t;
  float p0 = s0 + uss[ub]           + bias[c];
  float p1 = s1 + uss[ub + 1048576] + bias[1024 + c];
  float p2 = s2 + uss[ub + 2097152] + bias[2048 + c];
  float p3 = s3 + uss[ub + 3145728] + bias[3072 + c];
  float it = fsig(p0), ot = fsig(p1), g_ = ftanh(p2), ft = fsig(p3);
  float zc = t ? z1ss[(b * 2048 + 1024 + c) * 1024 + t - 1] : z0[b * 2048 + 1024 + c];
  float ct = ft * zc + it * g_;
  float ht = ot * ftanh(ct);
  int ob = (b * 2048 + c) * 1024 + t;
  out[ob] = ht;
  out[ob + 1048576] = ct;
}

extern "C" void kernel_launch(void* const* d_in, const int* in_sizes, int n_in,
                              void* d_out, int out_size, void* d_ws, size_t ws_size,
                              hipStream_t stream) {
  const float* z1ss = (const float*)d_in[0];
  const float* uss  = (const float*)d_in[1];
  const float* z0   = (const float*)d_in[2];
  const float* w    = (const float*)d_in[3];
  const float* bias = (const float*)d_in[4];
  float* out = (float*)d_out;

  const size_t needWb = (size_t)4096 * 2048 * 2;   // 16 MB bf16 weight
  const size_t needBd = (size_t)NTOT * K2 * 2;     // 32 MB bf16 B matrix
  if (ws_size >= needWb + needBd) {
    unsigned short* Wb = (unsigned short*)d_ws;
    unsigned short* Bd = Wb + (size_t)4096 * 2048;
    conv_weight_kernel<<<8192, 256, 0, stream>>>(w, (unsigned*)Wb);
    build_bdup_kernel<<<dim3(256, 32), 256, 0, stream>>>(z1ss, z0, (unsigned*)Bd);
    lstm_gemm_kernel<<<dim3(64, 32), 256, 0, stream>>>(Wb, Bd, uss, z1ss, z0, bias, out);
  } else {
    naive_kernel<<<32768, 256, 0, stream>>>(z1ss, uss, z0, w, bias, out);
  }
}

// Round 5
// 400.854 us; speedup vs baseline: 1.1325x; 1.1325x over previous
//
#include <hip/hip_runtime.h>
#include <hip/hip_bf16.h>
#include <cstdint>

// Problem constants (bsz=8, h=1024, seq=1024, K=2 taps)
#define HSZ   1024
#define SEQ   1024
#define NTOT  8192      // bsz*seq
#define K2    2048      // 2*h (i,tap interleaved)

typedef __attribute__((ext_vector_type(8))) short bf16x8;
typedef __attribute__((ext_vector_type(4))) float f32x4;

__device__ __forceinline__ unsigned f2bf(float x) {
  unsigned u = __builtin_bit_cast(unsigned, x);
  return (u + 0x7fffu + ((u >> 16) & 1u)) >> 16;   // RNE, inputs are finite
}
__device__ __forceinline__ float fsig(float x)  { return 1.f / (1.f + __expf(-x)); }
__device__ __forceinline__ float ftanh(float x) { return 1.f - 2.f / (__expf(2.f * x) + 1.f); }

__device__ __forceinline__ void gload_lds16(const void* g, void* l) {
  __builtin_amdgcn_global_load_lds(
      (const __attribute__((address_space(1))) unsigned*)g,
      (__attribute__((address_space(3))) unsigned*)l, 16, 0, 0);
}

// ---- prep 1: weight fp32 -> bf16 (vectorized: 8 floats/thread, uint4 store) ----
__global__ void conv_weight_kernel(const float* __restrict__ w, unsigned* __restrict__ wb) {
  const int idx = (blockIdx.x * 256 + threadIdx.x) * 8;  // 4096 blocks * 2048 floats = exact
  f32x4 a = *(const f32x4*)(w + idx);
  f32x4 c = *(const f32x4*)(w + idx + 4);
  uint4 o;
  o.x = f2bf(a.x) | (f2bf(a.y) << 16);
  o.y = f2bf(a.z) | (f2bf(a.w) << 16);
  o.z = f2bf(c.x) | (f2bf(c.y) << 16);
  o.w = f2bf(c.z) | (f2bf(c.w) << 16);
  *(uint4*)(wb + (idx >> 1)) = o;
}

// ---- prep 2: Bd[n][k] bf16, k=2i+tap: tap0 = x[t-1] (z0h at t=0), tap1 = x[t] ----
// v2: BW-limited form. Tile 32 i-rows x 64 t-cols per block (grid 128 x 32).
// Phase 1: float4-coalesced loads of z1h[t0..t0+63] (t0 mult of 64, 16B-aligned)
//   into LDS tile[32][65] (col 0 = t0-1, scalar edge load / z0h).
//   Stride 65 -> phase-2 bank index (i2*65+c) mod 32 = (i2+c) mod 32: permutation,
//   conflict-free.
// Phase 2: pack (prev,cur) bf16 pairs, store u32 with 32 consecutive i-lanes
//   (128B segments, coalesced).
__global__ void build_bdup_kernel(const float* __restrict__ z1ss, const float* __restrict__ z0,
                                  unsigned* __restrict__ bd) {
  __shared__ float tile[32 * 65];                    // [ii][c], c = local t + 1
  const int tid = threadIdx.x;
  const int n0 = blockIdx.x * 64;                    // 128 n-chunks (never cross batch)
  const int i0 = blockIdx.y * 32;                    // 32 i-chunks
  const int b  = n0 >> 10;
  const int t0 = n0 & 1023;
  const int l16 = tid & 15, r16 = tid >> 4;          // 16 rows per pass, 2 passes
#pragma unroll
  for (int pr = 0; pr < 2; ++pr) {
    const int ii = r16 + pr * 16;
    const float* zrow = z1ss + (size_t)(b * 2048 + i0 + ii) * 1024;
    f32x4 v = *(const f32x4*)(zrow + t0 + l16 * 4);
    float* tr = tile + ii * 65 + 1 + l16 * 4;
    tr[0] = v.x; tr[1] = v.y; tr[2] = v.z; tr[3] = v.w;
    if (l16 == 0)
      tile[ii * 65] = t0 ? zrow[t0 - 1] : z0[b * 2048 + i0 + ii];
  }
  __syncthreads();
  const int i2 = tid & 31, ts = tid >> 5;
#pragma unroll
  for (int p = 0; p < 8; ++p) {
    const int tt = ts + p * 8;
    float prev = tile[i2 * 65 + tt];                 // x[t0+tt-1] (or z0h)
    float cur  = tile[i2 * 65 + tt + 1];             // x[t0+tt]
    bd[(size_t)(n0 + tt) * 1024 + i0 + i2] = f2bf(prev) | (f2bf(cur) << 16);
  }
}

// ---- GEMM + fused LSTM epilogue (VERIFIED BEST: R3, 196 us — unchanged) ----
// m97-style 128x128 structure, BK=64: halves the per-block drain count vs BK=32
// (64 barriers/block) while LDS 32 KB + VGPR 64(+64 AGPR) keeps 4 blocks/CU —
// the cross-block overlap (m114) that hides the vmcnt(0) drains.
// Block: 128 A-rows (row = g*32+cc -> weight row g*1024+c0+cc) x 128 n-cols.
// Wave owns all 128 rows x 32 cols: acc[4][2][2] f32x4 = 64 regs/lane.
// LDS layout (A and B): row-major [128 rows][8 slots of 8 shorts],
//   slot = chunk ^ (row&7)  -> DMA-linear AND ds_read_b128 conflict-free
//   (measured SQ_LDS_BANK_CONFLICT = 0).
__launch_bounds__(256, 3)
__global__ void lstm_gemm_kernel(const unsigned short* __restrict__ Wb,
                                 const unsigned short* __restrict__ Bd,
                                 const float* __restrict__ uss,
                                 const float* __restrict__ z1ss,
                                 const float* __restrict__ z0,
                                 const float* __restrict__ bias,
                                 float* __restrict__ out) {
  __shared__ unsigned short Asm_[128 * 64];   // 16 KB, swizzled
  __shared__ unsigned short Bsm_[128 * 64];   // 16 KB, swizzled
  const int tid  = threadIdx.x;
  const int wave = tid >> 6, lane = tid & 63;
  const int l15  = lane & 15, quad = lane >> 4;
  const int c0 = blockIdx.y * 32;
  const int n0 = blockIdx.x * 128;

  // staging: per wave 4 A-insts + 4 B-insts, each covers 8 rows x 64k (1 KiB LDS)
  const unsigned short* agp[4];
  const unsigned short* bgp[4];
#pragma unroll
  for (int j = 0; j < 4; ++j) {
    const int idx = (wave * 4 + j) * 64 + lane;      // lds 16B-unit index in [0,1024)
    const int row = idx >> 3;                        // [0,128)
    const int chunk = (idx & 7) ^ (row & 7);         // global k-chunk this lane fetches
    const int wrow = (row >> 5) * 1024 + c0 + (row & 31);
    agp[j] = Wb + (size_t)wrow * K2 + chunk * 8;
    bgp[j] = Bd + (size_t)(n0 + row) * K2 + chunk * 8;
  }
  unsigned short* ldsA[4];
  unsigned short* ldsB[4];
#pragma unroll
  for (int j = 0; j < 4; ++j) {
    ldsA[j] = Asm_ + (wave * 4 + j) * 512;
    ldsB[j] = Bsm_ + (wave * 4 + j) * 512;
  }

  // fragment read offset: row r, k-half kh, lane quad:
  // shorts addr = r*64 + (((kh*4+quad) ^ (r&7)) << 3); r&7 == l15&7 for all frags.
  const int sw7 = l15 & 7;

  f32x4 acc[4][2][2];
#pragma unroll
  for (int g = 0; g < 4; ++g)
#pragma unroll
    for (int h = 0; h < 2; ++h)
#pragma unroll
      for (int nt = 0; nt < 2; ++nt)
        acc[g][h][nt] = (f32x4){0.f, 0.f, 0.f, 0.f};

  for (int k0 = 0; k0 < K2; k0 += 64) {
#pragma unroll
    for (int j = 0; j < 4; ++j) gload_lds16(agp[j] + k0, ldsA[j]);
#pragma unroll
    for (int j = 0; j < 4; ++j) gload_lds16(bgp[j] + k0, ldsB[j]);
    __syncthreads();                                  // drains vmcnt + barrier

#pragma unroll
    for (int kh = 0; kh < 2; ++kh) {
      const int slot = ((kh * 4 + quad) ^ sw7) << 3;  // shorts offset of 16B chunk
      bf16x8 bf[2];
#pragma unroll
      for (int nt = 0; nt < 2; ++nt) {
        const int br = wave * 32 + nt * 16 + l15;
        bf[nt] = *(const bf16x8*)(Bsm_ + br * 64 + slot);
      }
#pragma unroll
      for (int g = 0; g < 4; ++g)
#pragma unroll
        for (int h = 0; h < 2; ++h) {
          const int ar = (g * 2 + h) * 16 + l15;
          bf16x8 af = *(const bf16x8*)(Asm_ + ar * 64 + slot);
#pragma unroll
          for (int nt = 0; nt < 2; ++nt)
            acc[g][h][nt] = __builtin_amdgcn_mfma_f32_16x16x32_bf16(af, bf[nt], acc[g][h][nt], 0, 0, 0);
        }
    }
    __syncthreads();                                  // protect LDS before next stage
  }

  // epilogue: C/D layout col=lane&15 (n), row=quad*4+reg (m); all 4 gates register-local
#pragma unroll
  for (int h = 0; h < 2; ++h) {
#pragma unroll
    for (int r = 0; r < 4; ++r) {
      const int c = c0 + h * 16 + quad * 4 + r;
      const float bv0 = bias[c], bv1 = bias[1024 + c], bv2 = bias[2048 + c], bv3 = bias[3072 + c];
#pragma unroll
      for (int nt = 0; nt < 2; ++nt) {
        const int n = n0 + wave * 32 + nt * 16 + l15;
        const int b = n >> 10, t = n & 1023;
        const int ub = b * 4194304 + c * 1024 + t;   // uss[b][g*1024+c][t], gate stride 1048576
        float p0 = acc[0][h][nt][r] + uss[ub]           + bv0;
        float p1 = acc[1][h][nt][r] + uss[ub + 1048576] + bv1;
        float p2 = acc[2][h][nt][r] + uss[ub + 2097152] + bv2;
        float p3 = acc[3][h][nt][r] + uss[ub + 3145728] + bv3;
        float it = fsig(p0), ot = fsig(p1), g_ = ftanh(p2), ft = fsig(p3);
        float zc = t ? z1ss[(b * 2048 + 1024 + c) * 1024 + t - 1]
                     : z0[b * 2048 + 1024 + c];
        float ct = ft * zc + it * g_;
        float ht = ot * ftanh(ct);
        const int ob = (b * 2048 + c) * 1024 + t;
        out[ob] = ht;
        out[ob + 1048576] = ct;
      }
    }
  }
}

// ---- slow-but-correct fallback if ws too small ----
__global__ void naive_kernel(const float* __restrict__ z1ss, const float* __restrict__ uss,
                             const float* __restrict__ z0, const float* __restrict__ w,
                             const float* __restrict__ bias, float* __restrict__ out) {
  int idx = blockIdx.x * 256 + threadIdx.x;          // (b,c,t)
  int b = idx >> 20, c = (idx >> 10) & 1023, t = idx & 1023;
  float s0 = 0.f, s1 = 0.f, s2 = 0.f, s3 = 0.f;
  const float* xb = z1ss + b * 2097152;
  for (int i = 0; i < 1024; ++i) {
    float cur  = xb[i * 1024 + t];
    float prev = t ? xb[i * 1024 + t - 1] : z0[b * 2048 + i];
    const float* wr = w + c * 2048 + i * 2;
    s0 += wr[0]       * prev + wr[1]       * cur;
    s1 += wr[2097152] * prev + wr[2097153] * cur;
    s2 += wr[4194304] * prev + wr[4194305] * cur;
    s3 += wr[6291456] * prev + wr[6291457] * cur;
  }
  int ub = b * 4194304 + c * 1024 + t;
  float p0 = s0 + uss[ub]           + bias[c];
  float p1 = s1 + uss[ub + 1048576] + bias[1024 + c];
  float p2 = s2 + uss[ub + 2097152] + bias[2048 + c];
  float p3 = s3 + uss[ub + 3145728] + bias[3072 + c];
  float it = fsig(p0), ot = fsig(p1), g_ = ftanh(p2), ft = fsig(p3);
  float zc = t ? z1ss[(b * 2048 + 1024 + c) * 1024 + t - 1] : z0[b * 2048 + 1024 + c];
  float ct = ft * zc + it * g_;
  float ht = ot * ftanh(ct);
  int ob = (b * 2048 + c) * 1024 + t;
  out[ob] = ht;
  out[ob + 1048576] = ct;
}

extern "C" void kernel_launch(void* const* d_in, const int* in_sizes, int n_in,
                              void* d_out, int out_size, void* d_ws, size_t ws_size,
                              hipStream_t stream) {
  const float* z1ss = (const float*)d_in[0];
  const float* uss  = (const float*)d_in[1];
  const float* z0   = (const float*)d_in[2];
  const float* w    = (const float*)d_in[3];
  const float* bias = (const float*)d_in[4];
  float* out = (float*)d_out;

  const size_t needWb = (size_t)4096 * 2048 * 2;   // 16 MB bf16 weight
  const size_t needBd = (size_t)NTOT * K2 * 2;     // 32 MB bf16 B matrix
  if (ws_size >= needWb + needBd) {
    unsigned short* Wb = (unsigned short*)d_ws;
    unsigned short* Bd = Wb + (size_t)4096 * 2048;
    conv_weight_kernel<<<4096, 256, 0, stream>>>(w, (unsigned*)Wb);
    build_bdup_kernel<<<dim3(128, 32), 256, 0, stream>>>(z1ss, z0, (unsigned*)Bd);
    lstm_gemm_kernel<<<dim3(64, 32), 256, 0, stream>>>(Wb, Bd, uss, z1ss, z0, bias, out);
  } else {
    naive_kernel<<<32768, 256, 0, stream>>>(z1ss, uss, z0, w, bias, out);
  }
}

// Round 6
// 397.781 us; speedup vs baseline: 1.1413x; 1.0077x over previous
//
#include <hip/hip_runtime.h>
#include <hip/hip_bf16.h>
#include <cstdint>

// Problem constants (bsz=8, h=1024, seq=1024, K=2 taps)
#define HSZ   1024
#define SEQ   1024
#define NTOT  8192      // bsz*seq
#define K2    2048      // 2*h (i,tap interleaved)

typedef __attribute__((ext_vector_type(8))) short bf16x8;
typedef __attribute__((ext_vector_type(4))) float f32x4;

__device__ __forceinline__ unsigned f2bf(float x) {
  unsigned u = __builtin_bit_cast(unsigned, x);
  return (u + 0x7fffu + ((u >> 16) & 1u)) >> 16;   // RNE, inputs are finite
}
__device__ __forceinline__ float fsig(float x)  { return 1.f / (1.f + __expf(-x)); }
__device__ __forceinline__ float ftanh(float x) { return 1.f - 2.f / (__expf(2.f * x) + 1.f); }

__device__ __forceinline__ void gload_lds16(const void* g, void* l) {
  __builtin_amdgcn_global_load_lds(
      (const __attribute__((address_space(1))) unsigned*)g,
      (__attribute__((address_space(3))) unsigned*)l, 16, 0, 0);
}

// ---- prep 1: weight fp32 -> bf16, GATE-INTERLEAVED layout ----
// Input row o = g*1024 + c  ->  output row R = c*4 + g (k layout unchanged).
// A GEMM block's 128 A-rows (32 channels x 4 gates) are then a CONTIGUOUS
// Wb panel starting at row c0*4, and the C/D fragment's 4 regs become the
// 4 gates of one channel (epilogue register-local per f32x4).
__global__ void conv_weight_kernel(const float* __restrict__ w, unsigned* __restrict__ wb) {
  const int idx = (blockIdx.x * 256 + threadIdx.x) * 8;  // 4096 blocks * 2048 floats = exact
  const int o  = idx >> 11;                              // input row (g*1024+c)
  const int kk = idx & 2047;
  const int g = o >> 10, c = o & 1023;
  const int R = (c << 2) | g;                            // permuted output row
  f32x4 a = *(const f32x4*)(w + idx);
  f32x4 d = *(const f32x4*)(w + idx + 4);
  uint4 ov;
  ov.x = f2bf(a.x) | (f2bf(a.y) << 16);
  ov.y = f2bf(a.z) | (f2bf(a.w) << 16);
  ov.z = f2bf(d.x) | (f2bf(d.y) << 16);
  ov.w = f2bf(d.z) | (f2bf(d.w) << 16);
  *(uint4*)(wb + (((R << 11) | kk) >> 1)) = ov;          // kk mult of 8 -> 16B aligned
}

// ---- prep 2: Bd[n][k] bf16, k=2i+tap: tap0 = x[t-1] (z0h at t=0), tap1 = x[t] ----
// (unchanged from R5 — BW-limited form)
__global__ void build_bdup_kernel(const float* __restrict__ z1ss, const float* __restrict__ z0,
                                  unsigned* __restrict__ bd) {
  __shared__ float tile[32 * 65];                    // [ii][c], c = local t + 1
  const int tid = threadIdx.x;
  const int n0 = blockIdx.x * 64;                    // 128 n-chunks (never cross batch)
  const int i0 = blockIdx.y * 32;                    // 32 i-chunks
  const int b  = n0 >> 10;
  const int t0 = n0 & 1023;
  const int l16 = tid & 15, r16 = tid >> 4;          // 16 rows per pass, 2 passes
#pragma unroll
  for (int pr = 0; pr < 2; ++pr) {
    const int ii = r16 + pr * 16;
    const float* zrow = z1ss + (size_t)(b * 2048 + i0 + ii) * 1024;
    f32x4 v = *(const f32x4*)(zrow + t0 + l16 * 4);
    float* tr = tile + ii * 65 + 1 + l16 * 4;
    tr[0] = v.x; tr[1] = v.y; tr[2] = v.z; tr[3] = v.w;
    if (l16 == 0)
      tile[ii * 65] = t0 ? zrow[t0 - 1] : z0[b * 2048 + i0 + ii];
  }
  __syncthreads();
  const int i2 = tid & 31, ts = tid >> 5;
#pragma unroll
  for (int p = 0; p < 8; ++p) {
    const int tt = ts + p * 8;
    float prev = tile[i2 * 65 + tt];                 // x[t0+tt-1] (or z0h)
    float cur  = tile[i2 * 65 + tt + 1];             // x[t0+tt]
    bd[(size_t)(n0 + tt) * 1024 + i0 + i2] = f2bf(prev) | (f2bf(cur) << 16);
  }
}

// ---- GEMM + fused LSTM epilogue ----
// m97-family 128x128, BK=64 (proven 196-199 us), changed wave tiling:
// SYMMETRIC 64x64 per wave (2x2 wave grid) on gate-interleaved A rows.
//   per kh: 4 af + 4 bf ds_read_b128, 16 MFMA  -> 16 reads/K-step (was 20),
//   cutting the busiest pipe (LDS-read ~50% busy) by 20%.
// A rows: block row r = Wb row c0*4 + r = channel c0+(r>>2), gate r&3.
// C/D row = quad*4 + reg = 4*cc + g  =>  gate g == reg index: the 4 gates of
// channel c0 + wm*16 + m*4 + quad are the 4 floats of acc[m][nt].
// LDS layout unchanged: [128 rows][8 slots of 8 shorts], slot = chunk^(row&7),
// DMA-linear dest + pre-swizzled source, measured conflict-free.
__launch_bounds__(256, 3)
__global__ void lstm_gemm_kernel(const unsigned short* __restrict__ Wb,
                                 const unsigned short* __restrict__ Bd,
                                 const float* __restrict__ uss,
                                 const float* __restrict__ z1ss,
                                 const float* __restrict__ z0,
                                 const float* __restrict__ bias,
                                 float* __restrict__ out) {
  __shared__ unsigned short Asm_[128 * 64];   // 16 KB, swizzled
  __shared__ unsigned short Bsm_[128 * 64];   // 16 KB, swizzled
  const int tid  = threadIdx.x;
  const int wave = tid >> 6, lane = tid & 63;
  const int l15  = lane & 15, quad = lane >> 4;
  const int wm   = wave >> 1, wn = wave & 1;  // 2x2 wave grid
  const int c0 = blockIdx.y * 32;             // channel tile
  const int n0 = blockIdx.x * 128;

  // staging: per wave 4 A-insts + 4 B-insts, each covers 8 rows x 64k (1 KiB LDS)
  const unsigned short* agp[4];
  const unsigned short* bgp[4];
#pragma unroll
  for (int j = 0; j < 4; ++j) {
    const int idx = (wave * 4 + j) * 64 + lane;      // lds 16B-unit index in [0,1024)
    const int row = idx >> 3;                        // [0,128)
    const int chunk = (idx & 7) ^ (row & 7);         // global k-chunk this lane fetches
    agp[j] = Wb + (size_t)(c0 * 4 + row) * K2 + chunk * 8;   // contiguous panel
    bgp[j] = Bd + (size_t)(n0 + row) * K2 + chunk * 8;
  }
  unsigned short* ldsA[4];
  unsigned short* ldsB[4];
#pragma unroll
  for (int j = 0; j < 4; ++j) {
    ldsA[j] = Asm_ + (wave * 4 + j) * 512;
    ldsB[j] = Bsm_ + (wave * 4 + j) * 512;
  }

  // fragment read slot: read rows r have r&7 == l15&7 (bases mult of 16/64)
  const int sw7 = l15 & 7;

  f32x4 acc[4][4];
#pragma unroll
  for (int m = 0; m < 4; ++m)
#pragma unroll
    for (int nt = 0; nt < 4; ++nt)
      acc[m][nt] = (f32x4){0.f, 0.f, 0.f, 0.f};

  for (int k0 = 0; k0 < K2; k0 += 64) {
#pragma unroll
    for (int j = 0; j < 4; ++j) gload_lds16(agp[j] + k0, ldsA[j]);
#pragma unroll
    for (int j = 0; j < 4; ++j) gload_lds16(bgp[j] + k0, ldsB[j]);
    __syncthreads();                                  // drains vmcnt + barrier

#pragma unroll
    for (int kh = 0; kh < 2; ++kh) {
      const int slot = ((kh * 4 + quad) ^ sw7) << 3;  // shorts offset of 16B chunk
      bf16x8 bf[4];
#pragma unroll
      for (int nt = 0; nt < 4; ++nt)
        bf[nt] = *(const bf16x8*)(Bsm_ + (wn * 64 + nt * 16 + l15) * 64 + slot);
#pragma unroll
      for (int m = 0; m < 4; ++m) {
        bf16x8 af = *(const bf16x8*)(Asm_ + (wm * 64 + m * 16 + l15) * 64 + slot);
#pragma unroll
        for (int nt = 0; nt < 4; ++nt)
          acc[m][nt] = __builtin_amdgcn_mfma_f32_16x16x32_bf16(af, bf[nt], acc[m][nt], 0, 0, 0);
      }
    }
    __syncthreads();                                  // protect LDS before next stage
  }

  // epilogue: C/D col=l15 (n), row=quad*4+r; row = 4*cc_local + g  =>  g == r.
  // Cell (m,nt): channel ch = c0 + wm*16 + m*4 + quad, n = n0 + wn*64 + nt*16 + l15.
#pragma unroll
  for (int m = 0; m < 4; ++m) {
    const int ch = c0 + wm * 16 + m * 4 + quad;
    const float bv0 = bias[ch], bv1 = bias[1024 + ch], bv2 = bias[2048 + ch], bv3 = bias[3072 + ch];
#pragma unroll
    for (int nt = 0; nt < 4; ++nt) {
      const int n = n0 + wn * 64 + nt * 16 + l15;
      const int b = n >> 10, t = n & 1023;
      const int ub = b * 4194304 + ch * 1024 + t;    // uss[b][g*1024+ch][t], gate stride 1048576
      f32x4 ac = acc[m][nt];
      float p0 = ac.x + uss[ub]           + bv0;     // gate i (g=0)
      float p1 = ac.y + uss[ub + 1048576] + bv1;     // gate o (g=1)
      float p2 = ac.z + uss[ub + 2097152] + bv2;     // gate g (g=2)
      float p3 = ac.w + uss[ub + 3145728] + bv3;     // gate f (g=3)
      float it = fsig(p0), ot = fsig(p1), g_ = ftanh(p2), ft = fsig(p3);
      float zc = t ? z1ss[(b * 2048 + 1024 + ch) * 1024 + t - 1]
                   : z0[b * 2048 + 1024 + ch];
      float ct = ft * zc + it * g_;
      float ht = ot * ftanh(ct);
      const int ob = (b * 2048 + ch) * 1024 + t;
      out[ob] = ht;
      out[ob + 1048576] = ct;
    }
  }
}

// ---- slow-but-correct fallback if ws too small ----
__global__ void naive_kernel(const float* __restrict__ z1ss, const float* __restrict__ uss,
                             const float* __restrict__ z0, const float* __restrict__ w,
                             const float* __restrict__ bias, float* __restrict__ out) {
  int idx = blockIdx.x * 256 + threadIdx.x;          // (b,c,t)
  int b = idx >> 20, c = (idx >> 10) & 1023, t = idx & 1023;
  float s0 = 0.f, s1 = 0.f, s2 = 0.f, s3 = 0.f;
  const float* xb = z1ss + b * 2097152;
  for (int i = 0; i < 1024; ++i) {
    float cur  = xb[i * 1024 + t];
    float prev = t ? xb[i * 1024 + t - 1] : z0[b * 2048 + i];
    const float* wr = w + c * 2048 + i * 2;
    s0 += wr[0]       * prev + wr[1]       * cur;
    s1 += wr[2097152] * prev + wr[2097153] * cur;
    s2 += wr[4194304] * prev + wr[4194305] * cur;
    s3 += wr[6291456] * prev + wr[6291457] * cur;
  }
  int ub = b * 4194304 + c * 1024 + t;
  float p0 = s0 + uss[ub]           + bias[c];
  float p1 = s1 + uss[ub + 1048576] + bias[1024 + c];
  float p2 = s2 + uss[ub + 2097152] + bias[2048 + c];
  float p3 = s3 + uss[ub + 3145728] + bias[3072 + c];
  float it = fsig(p0), ot = fsig(p1), g_ = ftanh(p2), ft = fsig(p3);
  float zc = t ? z1ss[(b * 2048 + 1024 + c) * 1024 + t - 1] : z0[b * 2048 + 1024 + c];
  float ct = ft * zc + it * g_;
  float ht = ot * ftanh(ct);
  int ob = (b * 2048 + c) * 1024 + t;
  out[ob] = ht;
  out[ob + 1048576] = ct;
}

extern "C" void kernel_launch(void* const* d_in, const int* in_sizes, int n_in,
                              void* d_out, int out_size, void* d_ws, size_t ws_size,
                              hipStream_t stream) {
  const float* z1ss = (const float*)d_in[0];
  const float* uss  = (const float*)d_in[1];
  const float* z0   = (const float*)d_in[2];
  const float* w    = (const float*)d_in[3];
  const float* bias = (const float*)d_in[4];
  float* out = (float*)d_out;

  const size_t needWb = (size_t)4096 * 2048 * 2;   // 16 MB bf16 weight
  const size_t needBd = (size_t)NTOT * K2 * 2;     // 32 MB bf16 B matrix
  if (ws_size >= needWb + needBd) {
    unsigned short* Wb = (unsigned short*)d_ws;
    unsigned short* Bd = Wb + (size_t)4096 * 2048;
    conv_weight_kernel<<<4096, 256, 0, stream>>>(w, (unsigned*)Wb);
    build_bdup_kernel<<<dim3(128, 32), 256, 0, stream>>>(z1ss, z0, (unsigned*)Bd);
    lstm_gemm_kernel<<<dim3(64, 32), 256, 0, stream>>>(Wb, Bd, uss, z1ss, z0, bias, out);
  } else {
    naive_kernel<<<32768, 256, 0, stream>>>(z1ss, uss, z0, w, bias, out);
  }
}